// Round 3
// baseline (264.882 us; speedup 1.0000x reference)
//
#include <hip/hip_runtime.h>
#include <hip/hip_bf16.h>
#include <cmath>
#include <stdint.h>

#define B_ 8
#define T_ 2048
#define C_ 1024
#define HS_ 64
#define NS 8           // key splits per q-tile
#define LP 72          // attn LDS row stride in shorts

typedef __attribute__((ext_vector_type(8))) short short8;    // 8 bf16 (4 VGPRs) - MFMA A/B frag
typedef __attribute__((ext_vector_type(4))) float floatx4;   // MFMA C/D frag

__device__ inline unsigned short f2bf(float f) {
    union { float f; unsigned u; } v; v.f = f;
    unsigned r = v.u + 0x7FFF + ((v.u >> 16) & 1);   // RNE
    return (unsigned short)(r >> 16);
}
__device__ inline unsigned pk2bf(float a, float b) {   // -> v_cvt_pk_bf16_f32
    union { __hip_bfloat162 h; unsigned u; } v;
    v.h = __float22bfloat162_rn(float2{a, b});
    return v.u;
}
__device__ inline float bf2f(unsigned short u) {
    union { unsigned u; float f; } w; w.u = ((unsigned)u) << 16; return w.f;
}

// ---------------------------------------------------------------------------
// Kernel 1: W [C x HS] fp32 -> Wf in MFMA B-fragment order, bf16.
// Wf unit (ks, nt, lane) holds 8 bf16: W[ks*32 + (lane>>4)*8 + j][nt*16 + (lane&15)]
// so proj's B-frag load for (ks,nt) is ONE contiguous 1KB wave-load.
// 3 projections x 8192 units x 16B = 384 KB total, L2-resident in proj.
// ---------------------------------------------------------------------------
__global__ __launch_bounds__(256) void prep_wt(const float* __restrict__ Wq,
                                               const float* __restrict__ Wk,
                                               const float* __restrict__ Wv,
                                               unsigned short* __restrict__ wf) {
    int p   = blockIdx.x >> 4;        // 48 blocks: 3 proj x 16
    int blk = blockIdx.x & 15;
    const float* W = (p == 0) ? Wq : (p == 1) ? Wk : Wv;
    unsigned short* Wf = wf + p * 65536;
    #pragma unroll
    for (int u2 = 0; u2 < 2; ++u2) {
        int u = blk * 512 + u2 * 256 + threadIdx.x;   // 0..8191
        int lane = u & 63;
        int nt = (u >> 6) & 3;
        int ks = u >> 8;
        int l16 = lane & 15, quad = lane >> 4;
        int col  = nt * 16 + l16;
        int krow = ks * 32 + quad * 8;
        union { short8 s; unsigned short h[8]; } o;
        #pragma unroll
        for (int j = 0; j < 8; ++j)
            o.h[j] = f2bf(W[(krow + j) * 64 + col]);
        *(short8*)(Wf + (long)u * 8) = o.s;
    }
}

// ---------------------------------------------------------------------------
// Kernel 2: projections. X [16384x1024] fp32 @ W [1024x64] -> bf16 [16384x64]
//
// Round-3 structure: MLP-maximized. Diagnosis: rounds 0-2 (three different
// staging structures) all plateaued at ~2.4 TB/s effective read with every
// pipe <6% busy -> chip-wide latency x insufficient memory-level
// parallelism, not staging structure. m13's 6.3 TB/s copy had ~32 waves/CU
// and >64KB in flight per CU; we had ~25-50KB. This version: no LDS, no
// barriers, zero scattered loads (Wf is pre-formatted in fragment order so
// every B-load is a contiguous 1KB wave-load, L2-hot). Each wave: depth-4
// X prefetch queue (8 dwordx4 outstanding to HBM) + depth-2 Wf queue
// (8 x 1KB outstanding to L2), fully unrolled -> static reg indexing ->
// counted vmcnts, no drains. 12 waves/CU x ~12KB = ~144KB/CU in flight.
// grid = 768 (3 proj x 1024 wave-tiles / 4 waves), block = 256.
// ---------------------------------------------------------------------------
__global__ __launch_bounds__(256, 4) void proj_kernel(
    const float* __restrict__ qv, const float* __restrict__ kv, const float* __restrict__ vv,
    const unsigned short* __restrict__ wf,
    unsigned short* __restrict__ qb, unsigned short* __restrict__ kb, unsigned short* __restrict__ vb)
{
    const int tid  = threadIdx.x;
    const int wave = tid >> 6, lane = tid & 63, quad = lane >> 4, l16 = lane & 15;
    const int wid  = blockIdx.x * 4 + wave;     // 0..3071
    const int p    = wid >> 10;                 // projection
    const int tile = wid & 1023;                // 16-row tile

    const float* X = (p == 0) ? qv : (p == 1) ? kv : vv;
    unsigned short* Ob = (p == 0) ? qb : (p == 1) ? kb : vb;
    const unsigned short* Wf = wf + p * 65536;
    const float oscale = (p == 0) ? 0.125f : 1.0f;   // fold HS^-0.5 into Q

    // lane's A-source: row = tile*16 + l16, k-offset quad*8; 8 floats per step
    const float* xp = X + ((long)tile * 16 + l16) * C_ + quad * 8;
    // lane's B-source: fragment-ordered, 16B per (ks,nt)
    const unsigned short* wp = Wf + lane * 8;

    floatx4 acc[4] = { {0,0,0,0},{0,0,0,0},{0,0,0,0},{0,0,0,0} };

    // prefetch queues: X depth 4 steps (2 loads/step), Wf depth 2 steps (4/step)
    floatx4 xq[4][2];
    short8  wq[2][4];
    #pragma unroll
    for (int i = 0; i < 4; ++i) {
        xq[i][0] = *(const floatx4*)(xp + i * 32);
        xq[i][1] = *(const floatx4*)(xp + i * 32 + 4);
    }
    #pragma unroll
    for (int i = 0; i < 2; ++i)
        #pragma unroll
        for (int nt = 0; nt < 4; ++nt)
            wq[i][nt] = *(const short8*)(wp + (i * 4 + nt) * 512);

    #pragma unroll
    for (int ks = 0; ks < 32; ++ks) {
        const int xc = ks & 3, wc = ks & 1;
        floatx4 ca = xq[xc][0], cb = xq[xc][1];
        short8 b0 = wq[wc][0], b1 = wq[wc][1], b2 = wq[wc][2], b3 = wq[wc][3];

        if (ks + 4 < 32) {
            xq[xc][0] = *(const floatx4*)(xp + (ks + 4) * 32);
            xq[xc][1] = *(const floatx4*)(xp + (ks + 4) * 32 + 4);
        }
        if (ks + 2 < 32) {
            #pragma unroll
            for (int nt = 0; nt < 4; ++nt)
                wq[wc][nt] = *(const short8*)(wp + ((ks + 2) * 4 + nt) * 512);
        }

        union { short8 s; unsigned u[4]; } af;
        af.u[0] = pk2bf(ca[0], ca[1]);
        af.u[1] = pk2bf(ca[2], ca[3]);
        af.u[2] = pk2bf(cb[0], cb[1]);
        af.u[3] = pk2bf(cb[2], cb[3]);

        acc[0] = __builtin_amdgcn_mfma_f32_16x16x32_bf16(af.s, b0, acc[0], 0, 0, 0);
        acc[1] = __builtin_amdgcn_mfma_f32_16x16x32_bf16(af.s, b1, acc[1], 0, 0, 0);
        acc[2] = __builtin_amdgcn_mfma_f32_16x16x32_bf16(af.s, b2, acc[2], 0, 0, 0);
        acc[3] = __builtin_amdgcn_mfma_f32_16x16x32_bf16(af.s, b3, acc[3], 0, 0, 0);
    }

    // C layout: row = tile*16 + quad*4 + r, col = nt*16 + l16
    unsigned short* op = Ob + ((long)tile * 16 + quad * 4) * HS_ + l16;
    #pragma unroll
    for (int nt = 0; nt < 4; ++nt)
        #pragma unroll
        for (int r = 0; r < 4; ++r)
            op[r * HS_ + nt * 16] = f2bf(acc[nt][r] * oscale);
}

// ---------------------------------------------------------------------------
// Kernel 3a: flash attention partials with key-split.
// grid = 8b x 32qt x NS splits = 2048 WGs, block = 256 (4 waves x 16 q-rows).
// ---------------------------------------------------------------------------
__global__ __launch_bounds__(256) void attn_partial(
    const unsigned short* __restrict__ qb, const unsigned short* __restrict__ kb,
    const unsigned short* __restrict__ vb, const int* __restrict__ mask,
    unsigned short* __restrict__ Opart, float* __restrict__ Mpart, float* __restrict__ Lpart)
{
    const int s  = blockIdx.x & (NS - 1);
    const int bq = blockIdx.x >> 3;          // b*32 + qt
    const int qt = bq & 31;
    const int b  = bq >> 5;
    if (s > qt) return;                       // empty split; combine skips it

    __shared__ unsigned short Klds[64 * LP];      // K chunk [key][feat]
    __shared__ unsigned short Vt[64 * LP];        // V chunk transposed [feat][key]
    __shared__ unsigned short Plds[4][16 * LP];   // per-wave P scratch [qrow][key]

    const int tid = threadIdx.x;
    const int wave = tid >> 6, lane = tid & 63, quad = lane >> 4, l16 = lane & 15;

    // Q fragments (A-operand: m = l16, k = quad*8+j); scale folded in.
    const int qrow = qt * 64 + wave * 16 + l16;
    const unsigned short* qp = qb + ((long)(b * T_ + qrow)) * HS_;
    short8 aq0 = *(const short8*)&qp[0  + quad * 8];
    short8 aq1 = *(const short8*)&qp[32 + quad * 8];

    floatx4 acc_o[4] = { {0,0,0,0},{0,0,0,0},{0,0,0,0},{0,0,0,0} };
    float m_r[4] = { -INFINITY, -INFINITY, -INFINITY, -INFINITY };
    float l_r[4] = { 0.f, 0.f, 0.f, 0.f };

    const int rowg = qt * 64 + wave * 16 + quad * 4;

    const int skey = tid >> 3;
    const int sf8  = (tid & 7) * 8;
    const int vp = tid & 31, vg = tid >> 5;

    for (int c = s; c <= qt; c += NS) {
        const int kc = c * 64;
        #pragma unroll
        for (int it = 0; it < 2; ++it) {
            int key = it * 32 + skey;
            *(short8*)&Klds[key * LP + sf8] =
                *(const short8*)&kb[((long)(b * T_ + kc + key)) * HS_ + sf8];
        }
        {
            const unsigned short* v0p = &vb[((long)(b * T_ + kc + 2 * vp)) * HS_ + vg * 8];
            short8 v0 = *(const short8*)v0p;
            short8 v1 = *(const short8*)(v0p + HS_);
            #pragma unroll
            for (int j = 0; j < 8; ++j) {
                unsigned pr = (unsigned)(unsigned short)v0[j] |
                              ((unsigned)(unsigned short)v1[j] << 16);
                *(unsigned*)&Vt[(vg * 8 + j) * LP + 2 * vp] = pr;
            }
        }
        __syncthreads();

        floatx4 sv[4];
        #pragma unroll
        for (int kt = 0; kt < 4; ++kt) {
            floatx4 a = {0.f, 0.f, 0.f, 0.f};
            short8 bk0 = *(short8*)&Klds[(kt * 16 + l16) * LP + 0  + quad * 8];
            short8 bk1 = *(short8*)&Klds[(kt * 16 + l16) * LP + 32 + quad * 8];
            a = __builtin_amdgcn_mfma_f32_16x16x32_bf16(aq0, bk0, a, 0, 0, 0);
            a = __builtin_amdgcn_mfma_f32_16x16x32_bf16(aq1, bk1, a, 0, 0, 0);
            sv[kt] = a;
        }

        const bool lastc = (c == qt);
        #pragma unroll
        for (int kt = 0; kt < 4; ++kt) {
            int key = kc + kt * 16 + l16;
            int mk = mask[b * T_ + key];
            #pragma unroll
            for (int r = 0; r < 4; ++r) {
                bool dead = (mk == 0) || (lastc && key > rowg + r);
                if (dead) sv[kt][r] = -INFINITY;
            }
        }

        float alpha[4];
        #pragma unroll
        for (int r = 0; r < 4; ++r) {
            float mx = fmaxf(fmaxf(sv[0][r], sv[1][r]), fmaxf(sv[2][r], sv[3][r]));
            #pragma unroll
            for (int off = 1; off < 16; off <<= 1)
                mx = fmaxf(mx, __shfl_xor(mx, off));
            float mn = fmaxf(m_r[r], mx);
            float a_ = __expf(m_r[r] - mn);
            float ps = 0.f;
            #pragma unroll
            for (int kt = 0; kt < 4; ++kt) {
                float pv = __expf(sv[kt][r] - mn);
                sv[kt][r] = pv;
                ps += pv;
            }
            #pragma unroll
            for (int off = 1; off < 16; off <<= 1)
                ps += __shfl_xor(ps, off);
            l_r[r] = l_r[r] * a_ + ps;
            m_r[r] = mn;
            alpha[r] = a_;
        }
        #pragma unroll
        for (int nt = 0; nt < 4; ++nt)
            #pragma unroll
            for (int r = 0; r < 4; ++r)
                acc_o[nt][r] *= alpha[r];

        unsigned short* pl = Plds[wave];
        #pragma unroll
        for (int kt = 0; kt < 4; ++kt)
            #pragma unroll
            for (int r = 0; r < 4; ++r)
                pl[(quad * 4 + r) * LP + kt * 16 + l16] = f2bf(sv[kt][r]);
        short8 ap0 = *(short8*)&pl[l16 * LP + 0  + quad * 8];
        short8 ap1 = *(short8*)&pl[l16 * LP + 32 + quad * 8];

        #pragma unroll
        for (int nt = 0; nt < 4; ++nt) {
            short8 bv0 = *(short8*)&Vt[(nt * 16 + l16) * LP + 0  + quad * 8];
            short8 bv1 = *(short8*)&Vt[(nt * 16 + l16) * LP + 32 + quad * 8];
            acc_o[nt] = __builtin_amdgcn_mfma_f32_16x16x32_bf16(ap0, bv0, acc_o[nt], 0, 0, 0);
            acc_o[nt] = __builtin_amdgcn_mfma_f32_16x16x32_bf16(ap1, bv1, acc_o[nt], 0, 0, 0);
        }
        __syncthreads();
    }

    // write partials: O unnormalized (bf16), m/l fp32
    unsigned short* Op = Opart + (long)blockIdx.x * 4096;
    #pragma unroll
    for (int nt = 0; nt < 4; ++nt)
        #pragma unroll
        for (int r = 0; r < 4; ++r)
            Op[(wave * 16 + quad * 4 + r) * 64 + nt * 16 + l16] = f2bf(acc_o[nt][r]);
    if (l16 == 0) {
        #pragma unroll
        for (int r = 0; r < 4; ++r) {
            int rl = wave * 16 + quad * 4 + r;
            Mpart[(long)blockIdx.x * 64 + rl] = m_r[r];
            Lpart[(long)blockIdx.x * 64 + rl] = l_r[r];
        }
    }
}

// ---------------------------------------------------------------------------
// Kernel 3b: combine split partials. grid = 8b x 32qt x 2 = 512, block = 256.
// ---------------------------------------------------------------------------
__global__ __launch_bounds__(256) void attn_combine(
    const unsigned short* __restrict__ Opart, const float* __restrict__ Mpart,
    const float* __restrict__ Lpart, float* __restrict__ out)
{
    const int half = blockIdx.x & 1;
    const int bq = blockIdx.x >> 1;
    const int qt = bq & 31;
    const int b  = bq >> 5;
    const int nsp = (qt + 1 < NS) ? qt + 1 : NS;

    const int row  = (threadIdx.x >> 3) + half * 32;   // 0..63
    const int colg = (threadIdx.x & 7) * 8;
    const long base = (long)bq * NS;

    float M = -INFINITY;
    #pragma unroll
    for (int sp = 0; sp < NS; ++sp)
        if (sp < nsp) M = fmaxf(M, Mpart[(base + sp) * 64 + row]);

    float w[NS];
    float L = 0.f;
    #pragma unroll
    for (int sp = 0; sp < NS; ++sp)
        if (sp < nsp) {
            float e = __expf(Mpart[(base + sp) * 64 + row] - M);
            w[sp] = e;
            L += e * Lpart[(base + sp) * 64 + row];
        }

    float acc[8] = {0,0,0,0,0,0,0,0};
    #pragma unroll
    for (int sp = 0; sp < NS; ++sp)
        if (sp < nsp) {
            const unsigned short* Op = Opart + (base + sp) * 4096 + row * 64 + colg;
            short8 o = *(const short8*)Op;
            float ws = w[sp];
            #pragma unroll
            for (int j = 0; j < 8; ++j)
                acc[j] += ws * bf2f((unsigned short)o[j]);
        }

    float inv = 1.0f / L;
    float* op = out + ((long)(b * T_ + qt * 64 + row)) * HS_ + colg;
    floatx4 o0 = { acc[0] * inv, acc[1] * inv, acc[2] * inv, acc[3] * inv };
    floatx4 o1 = { acc[4] * inv, acc[5] * inv, acc[6] * inv, acc[7] * inv };
    *(floatx4*)op = o0;
    *(floatx4*)(op + 4) = o1;
}

// ---------------------------------------------------------------------------
extern "C" void kernel_launch(void* const* d_in, const int* in_sizes, int n_in,
                              void* d_out, int out_size, void* d_ws, size_t ws_size,
                              hipStream_t stream)
{
    const float* qv = (const float*)d_in[0];
    const float* kv = (const float*)d_in[1];
    const float* vv = (const float*)d_in[2];
    const int*   mask = (const int*)d_in[3];
    const float* Wq = (const float*)d_in[4];
    const float* Wk = (const float*)d_in[5];
    const float* Wv = (const float*)d_in[6];
    float* out = (float*)d_out;

    // ws layout: Wf x3 | q/k/v bf16 | O partials bf16 | M,L fp32  (~24.2 MB)
    unsigned short* wf    = (unsigned short*)d_ws;
    unsigned short* qbuf  = wf + 3 * C_ * HS_;
    unsigned short* kbuf  = qbuf + (long)B_ * T_ * HS_;
    unsigned short* vbuf  = kbuf + (long)B_ * T_ * HS_;
    unsigned short* Opart = vbuf + (long)B_ * T_ * HS_;
    float* Mpart = (float*)(Opart + (long)B_ * 32 * NS * 4096);
    float* Lpart = Mpart + (long)B_ * 32 * NS * 64;

    prep_wt<<<48, 256, 0, stream>>>(Wq, Wk, Wv, wf);
    proj_kernel<<<768, 256, 0, stream>>>(qv, kv, vv, wf, qbuf, kbuf, vbuf);
    attn_partial<<<B_ * 32 * NS, 256, 0, stream>>>(qbuf, kbuf, vbuf, mask, Opart, Mpart, Lpart);
    attn_combine<<<B_ * 32 * 2, 256, 0, stream>>>(Opart, Mpart, Lpart, out);
}

// Round 5
// 252.091 us; speedup vs baseline: 1.0507x; 1.0507x over previous
//
#include <hip/hip_runtime.h>
#include <hip/hip_bf16.h>
#include <cmath>
#include <stdint.h>

#define B_ 8
#define T_ 2048
#define C_ 1024
#define HS_ 64
#define NS 8           // key splits per q-tile
#define LP 72          // attn LDS row stride in shorts

typedef __attribute__((ext_vector_type(8))) short short8;    // 8 bf16 (4 VGPRs) - MFMA A/B frag
typedef __attribute__((ext_vector_type(4))) float floatx4;   // MFMA C/D frag

__device__ inline unsigned short f2bf(float f) {
    union { float f; unsigned u; } v; v.f = f;
    unsigned r = v.u + 0x7FFF + ((v.u >> 16) & 1);   // RNE
    return (unsigned short)(r >> 16);
}
__device__ inline unsigned pk2bf(float a, float b) {   // -> v_cvt_pk_bf16_f32
    union { __hip_bfloat162 h; unsigned u; } v;
    v.h = __float22bfloat162_rn(float2{a, b});
    return v.u;
}
__device__ inline float bf2f(unsigned short u) {
    union { unsigned u; float f; } w; w.u = ((unsigned)u) << 16; return w.f;
}

// ---------------------------------------------------------------------------
// Kernel 1: W [C x HS] fp32 -> Wf in MFMA B-fragment order, bf16.
// Wf unit (ks, nt, lane=quad*16+l16) holds 8 bf16:
//   W[ks*32 + quad*8 + j][nt*16 + l16],  j = 0..7
// so proj's B-frag load for (ks,nt) is ONE contiguous 1KB wave-load.
// Coalesced fp32 reads, scattered 2B writes (0.75 MB total, write-combined).
// ---------------------------------------------------------------------------
__global__ __launch_bounds__(256) void prep_wt(const float* __restrict__ Wq,
                                               const float* __restrict__ Wk,
                                               const float* __restrict__ Wv,
                                               unsigned short* __restrict__ wf) {
    int p   = blockIdx.x >> 4;        // 48 blocks: 3 proj x 16
    int blk = blockIdx.x & 15;
    const float* W = (p == 0) ? Wq : (p == 1) ? Wk : Wv;
    unsigned short* Wf = wf + p * 65536;
    #pragma unroll
    for (int it = 0; it < 16; ++it) {
        int idx = blk * 4096 + it * 256 + threadIdx.x;   // 0..65535, coalesced read
        int k = idx >> 6, col = idx & 63;
        int ks = k >> 5, quad = (k >> 3) & 3, j = k & 7;
        int nt = col >> 4, l16 = col & 15;
        Wf[(ks * 256 + nt * 64 + quad * 16 + l16) * 8 + j] = f2bf(W[idx]);
    }
}

// ---------------------------------------------------------------------------
// Kernel 2: projections. X [16384x1024] fp32 @ W [1024x64] -> bf16 [16384x64]
//
// Round-5: TLP-maximized via 4-way K-split. Evidence trail: rounds 0-3
// tried 4 staging structures, all ~2.4 TB/s effective with every pipe idle.
// Round-3's VGPR_Count=32 showed the compiler deletes source-level prefetch
// queues -> ~1-2 loads in flight per wave (192 KB/wave over 82.6us = one
// serialized ~430ns load at a time), and 12 waves/CU (grid=768) cannot
// cover that. Fix: raise wave count. Each wave computes 16 rows x K=256
// (8 MFMA steps); the block's 4 waves reduce through LDS (one barrier).
// Grid = 3072 blocks = 12 queued/CU; __launch_bounds__(256,6) -> 6 resident
// blocks/CU = 24 waves/CU (2x round-3) with VGPR cap 84 (est. use ~75, no
// spill). 24 waves x ~3KB in flight ~= 72 KB/CU >> 9-27 KB Little's-law
// requirement at loaded latency.
// ---------------------------------------------------------------------------
__global__ __launch_bounds__(256, 6) void proj_kernel(
    const float* __restrict__ qv, const float* __restrict__ kv, const float* __restrict__ vv,
    const unsigned short* __restrict__ wf,
    unsigned short* __restrict__ qb, unsigned short* __restrict__ kb, unsigned short* __restrict__ vb)
{
    __shared__ float rlds[3][16][68];   // 13 KB; 68-col stride -> worst 2-way (free)

    const int tid  = threadIdx.x;
    const int wave = tid >> 6, lane = tid & 63, quad = lane >> 4, l16 = lane & 15;
    const int p    = blockIdx.x >> 10;          // projection (1024 tiles each)
    const int tile = blockIdx.x & 1023;         // 16-row tile

    const float* X = (p == 0) ? qv : (p == 1) ? kv : vv;
    unsigned short* Ob = (p == 0) ? qb : (p == 1) ? kb : vb;
    const unsigned short* Wf = wf + p * 65536;
    const float oscale = (p == 0) ? 0.125f : 1.0f;   // fold HS^-0.5 into Q

    // wave owns K quarter [wave*256, wave*256+256)
    // lane's A-source: row = tile*16 + l16, k = wave*256 + s*32 + quad*8 + j
    const float* xp = X + ((long)tile * 16 + l16) * C_ + wave * 256 + quad * 8;
    // lane's B-source: fragment-ordered; global step ks = wave*8 + s
    const unsigned short* wp = Wf + (wave * 8) * 4 * 512 + lane * 8;

    floatx4 acc[4] = { {0,0,0,0},{0,0,0,0},{0,0,0,0},{0,0,0,0} };

    // depth-2 double buffers for both streams
    floatx4 xq[2][2];
    short8  wq[2][4];
    xq[0][0] = *(const floatx4*)(xp);
    xq[0][1] = *(const floatx4*)(xp + 4);
    xq[1][0] = *(const floatx4*)(xp + 32);
    xq[1][1] = *(const floatx4*)(xp + 36);
    #pragma unroll
    for (int nt = 0; nt < 4; ++nt) wq[0][nt] = *(const short8*)(wp + nt * 512);
    #pragma unroll
    for (int nt = 0; nt < 4; ++nt) wq[1][nt] = *(const short8*)(wp + (4 + nt) * 512);

    #pragma unroll
    for (int s = 0; s < 8; ++s) {
        const int bi = s & 1;
        floatx4 ca = xq[bi][0], cb = xq[bi][1];
        short8 b0 = wq[bi][0], b1 = wq[bi][1], b2 = wq[bi][2], b3 = wq[bi][3];

        if (s + 2 < 8) {
            xq[bi][0] = *(const floatx4*)(xp + (s + 2) * 32);
            xq[bi][1] = *(const floatx4*)(xp + (s + 2) * 32 + 4);
            #pragma unroll
            for (int nt = 0; nt < 4; ++nt)
                wq[bi][nt] = *(const short8*)(wp + ((s + 2) * 4 + nt) * 512);
        }

        union { short8 s8; unsigned u[4]; } af;
        af.u[0] = pk2bf(ca[0], ca[1]);
        af.u[1] = pk2bf(ca[2], ca[3]);
        af.u[2] = pk2bf(cb[0], cb[1]);
        af.u[3] = pk2bf(cb[2], cb[3]);

        acc[0] = __builtin_amdgcn_mfma_f32_16x16x32_bf16(af.s8, b0, acc[0], 0, 0, 0);
        acc[1] = __builtin_amdgcn_mfma_f32_16x16x32_bf16(af.s8, b1, acc[1], 0, 0, 0);
        acc[2] = __builtin_amdgcn_mfma_f32_16x16x32_bf16(af.s8, b2, acc[2], 0, 0, 0);
        acc[3] = __builtin_amdgcn_mfma_f32_16x16x32_bf16(af.s8, b3, acc[3], 0, 0, 0);
    }

    // 4-way K reduction through LDS (one barrier)
    if (wave) {
        #pragma unroll
        for (int nt = 0; nt < 4; ++nt)
            #pragma unroll
            for (int r = 0; r < 4; ++r)
                rlds[wave - 1][quad * 4 + r][nt * 16 + l16] = acc[nt][r];
    }
    __syncthreads();
    if (wave == 0) {
        #pragma unroll
        for (int nt = 0; nt < 4; ++nt)
            #pragma unroll
            for (int r = 0; r < 4; ++r)
                acc[nt][r] += rlds[0][quad * 4 + r][nt * 16 + l16]
                            + rlds[1][quad * 4 + r][nt * 16 + l16]
                            + rlds[2][quad * 4 + r][nt * 16 + l16];

        // C layout: row = tile*16 + quad*4 + r, col = nt*16 + l16
        unsigned short* op = Ob + ((long)tile * 16 + quad * 4) * HS_ + l16;
        #pragma unroll
        for (int nt = 0; nt < 4; ++nt)
            #pragma unroll
            for (int r = 0; r < 4; ++r)
                op[r * HS_ + nt * 16] = f2bf(acc[nt][r] * oscale);
    }
}

// ---------------------------------------------------------------------------
// Kernel 3a: flash attention partials with key-split.
// grid = 8b x 32qt x NS splits = 2048 WGs, block = 256 (4 waves x 16 q-rows).
// ---------------------------------------------------------------------------
__global__ __launch_bounds__(256) void attn_partial(
    const unsigned short* __restrict__ qb, const unsigned short* __restrict__ kb,
    const unsigned short* __restrict__ vb, const int* __restrict__ mask,
    unsigned short* __restrict__ Opart, float* __restrict__ Mpart, float* __restrict__ Lpart)
{
    const int s  = blockIdx.x & (NS - 1);
    const int bq = blockIdx.x >> 3;          // b*32 + qt
    const int qt = bq & 31;
    const int b  = bq >> 5;
    if (s > qt) return;                       // empty split; combine skips it

    __shared__ unsigned short Klds[64 * LP];      // K chunk [key][feat]
    __shared__ unsigned short Vt[64 * LP];        // V chunk transposed [feat][key]
    __shared__ unsigned short Plds[4][16 * LP];   // per-wave P scratch [qrow][key]

    const int tid = threadIdx.x;
    const int wave = tid >> 6, lane = tid & 63, quad = lane >> 4, l16 = lane & 15;

    // Q fragments (A-operand: m = l16, k = quad*8+j); scale folded in.
    const int qrow = qt * 64 + wave * 16 + l16;
    const unsigned short* qp = qb + ((long)(b * T_ + qrow)) * HS_;
    short8 aq0 = *(const short8*)&qp[0  + quad * 8];
    short8 aq1 = *(const short8*)&qp[32 + quad * 8];

    floatx4 acc_o[4] = { {0,0,0,0},{0,0,0,0},{0,0,0,0},{0,0,0,0} };
    float m_r[4] = { -INFINITY, -INFINITY, -INFINITY, -INFINITY };
    float l_r[4] = { 0.f, 0.f, 0.f, 0.f };

    const int rowg = qt * 64 + wave * 16 + quad * 4;

    const int skey = tid >> 3;
    const int sf8  = (tid & 7) * 8;
    const int vp = tid & 31, vg = tid >> 5;

    for (int c = s; c <= qt; c += NS) {
        const int kc = c * 64;
        #pragma unroll
        for (int it = 0; it < 2; ++it) {
            int key = it * 32 + skey;
            *(short8*)&Klds[key * LP + sf8] =
                *(const short8*)&kb[((long)(b * T_ + kc + key)) * HS_ + sf8];
        }
        {
            const unsigned short* v0p = &vb[((long)(b * T_ + kc + 2 * vp)) * HS_ + vg * 8];
            short8 v0 = *(const short8*)v0p;
            short8 v1 = *(const short8*)(v0p + HS_);
            #pragma unroll
            for (int j = 0; j < 8; ++j) {
                unsigned pr = (unsigned)(unsigned short)v0[j] |
                              ((unsigned)(unsigned short)v1[j] << 16);
                *(unsigned*)&Vt[(vg * 8 + j) * LP + 2 * vp] = pr;
            }
        }
        __syncthreads();

        floatx4 sv[4];
        #pragma unroll
        for (int kt = 0; kt < 4; ++kt) {
            floatx4 a = {0.f, 0.f, 0.f, 0.f};
            short8 bk0 = *(short8*)&Klds[(kt * 16 + l16) * LP + 0  + quad * 8];
            short8 bk1 = *(short8*)&Klds[(kt * 16 + l16) * LP + 32 + quad * 8];
            a = __builtin_amdgcn_mfma_f32_16x16x32_bf16(aq0, bk0, a, 0, 0, 0);
            a = __builtin_amdgcn_mfma_f32_16x16x32_bf16(aq1, bk1, a, 0, 0, 0);
            sv[kt] = a;
        }

        const bool lastc = (c == qt);
        #pragma unroll
        for (int kt = 0; kt < 4; ++kt) {
            int key = kc + kt * 16 + l16;
            int mk = mask[b * T_ + key];
            #pragma unroll
            for (int r = 0; r < 4; ++r) {
                bool dead = (mk == 0) || (lastc && key > rowg + r);
                if (dead) sv[kt][r] = -INFINITY;
            }
        }

        float alpha[4];
        #pragma unroll
        for (int r = 0; r < 4; ++r) {
            float mx = fmaxf(fmaxf(sv[0][r], sv[1][r]), fmaxf(sv[2][r], sv[3][r]));
            #pragma unroll
            for (int off = 1; off < 16; off <<= 1)
                mx = fmaxf(mx, __shfl_xor(mx, off));
            float mn = fmaxf(m_r[r], mx);
            float a_ = __expf(m_r[r] - mn);
            float ps = 0.f;
            #pragma unroll
            for (int kt = 0; kt < 4; ++kt) {
                float pv = __expf(sv[kt][r] - mn);
                sv[kt][r] = pv;
                ps += pv;
            }
            #pragma unroll
            for (int off = 1; off < 16; off <<= 1)
                ps += __shfl_xor(ps, off);
            l_r[r] = l_r[r] * a_ + ps;
            m_r[r] = mn;
            alpha[r] = a_;
        }
        #pragma unroll
        for (int nt = 0; nt < 4; ++nt)
            #pragma unroll
            for (int r = 0; r < 4; ++r)
                acc_o[nt][r] *= alpha[r];

        unsigned short* pl = Plds[wave];
        #pragma unroll
        for (int kt = 0; kt < 4; ++kt)
            #pragma unroll
            for (int r = 0; r < 4; ++r)
                pl[(quad * 4 + r) * LP + kt * 16 + l16] = f2bf(sv[kt][r]);
        short8 ap0 = *(short8*)&pl[l16 * LP + 0  + quad * 8];
        short8 ap1 = *(short8*)&pl[l16 * LP + 32 + quad * 8];

        #pragma unroll
        for (int nt = 0; nt < 4; ++nt) {
            short8 bv0 = *(short8*)&Vt[(nt * 16 + l16) * LP + 0  + quad * 8];
            short8 bv1 = *(short8*)&Vt[(nt * 16 + l16) * LP + 32 + quad * 8];
            acc_o[nt] = __builtin_amdgcn_mfma_f32_16x16x32_bf16(ap0, bv0, acc_o[nt], 0, 0, 0);
            acc_o[nt] = __builtin_amdgcn_mfma_f32_16x16x32_bf16(ap1, bv1, acc_o[nt], 0, 0, 0);
        }
        __syncthreads();
    }

    // write partials: O unnormalized (bf16), m/l fp32
    unsigned short* Op = Opart + (long)blockIdx.x * 4096;
    #pragma unroll
    for (int nt = 0; nt < 4; ++nt)
        #pragma unroll
        for (int r = 0; r < 4; ++r)
            Op[(wave * 16 + quad * 4 + r) * 64 + nt * 16 + l16] = f2bf(acc_o[nt][r]);
    if (l16 == 0) {
        #pragma unroll
        for (int r = 0; r < 4; ++r) {
            int rl = wave * 16 + quad * 4 + r;
            Mpart[(long)blockIdx.x * 64 + rl] = m_r[r];
            Lpart[(long)blockIdx.x * 64 + rl] = l_r[r];
        }
    }
}

// ---------------------------------------------------------------------------
// Kernel 3b: combine split partials. grid = 8b x 32qt x 2 = 512, block = 256.
// ---------------------------------------------------------------------------
__global__ __launch_bounds__(256) void attn_combine(
    const unsigned short* __restrict__ Opart, const float* __restrict__ Mpart,
    const float* __restrict__ Lpart, float* __restrict__ out)
{
    const int half = blockIdx.x & 1;
    const int bq = blockIdx.x >> 1;
    const int qt = bq & 31;
    const int b  = bq >> 5;
    const int nsp = (qt + 1 < NS) ? qt + 1 : NS;

    const int row  = (threadIdx.x >> 3) + half * 32;   // 0..63
    const int colg = (threadIdx.x & 7) * 8;
    const long base = (long)bq * NS;

    float M = -INFINITY;
    #pragma unroll
    for (int sp = 0; sp < NS; ++sp)
        if (sp < nsp) M = fmaxf(M, Mpart[(base + sp) * 64 + row]);

    float w[NS];
    float L = 0.f;
    #pragma unroll
    for (int sp = 0; sp < NS; ++sp)
        if (sp < nsp) {
            float e = __expf(Mpart[(base + sp) * 64 + row] - M);
            w[sp] = e;
            L += e * Lpart[(base + sp) * 64 + row];
        }

    float acc[8] = {0,0,0,0,0,0,0,0};
    #pragma unroll
    for (int sp = 0; sp < NS; ++sp)
        if (sp < nsp) {
            const unsigned short* Op = Opart + (base + sp) * 4096 + row * 64 + colg;
            short8 o = *(const short8*)Op;
            float ws = w[sp];
            #pragma unroll
            for (int j = 0; j < 8; ++j)
                acc[j] += ws * bf2f((unsigned short)o[j]);
        }

    float inv = 1.0f / L;
    float* op = out + ((long)(b * T_ + qt * 64 + row)) * HS_ + colg;
    floatx4 o0 = { acc[0] * inv, acc[1] * inv, acc[2] * inv, acc[3] * inv };
    floatx4 o1 = { acc[4] * inv, acc[5] * inv, acc[6] * inv, acc[7] * inv };
    *(floatx4*)op = o0;
    *(floatx4*)(op + 4) = o1;
}

// ---------------------------------------------------------------------------
extern "C" void kernel_launch(void* const* d_in, const int* in_sizes, int n_in,
                              void* d_out, int out_size, void* d_ws, size_t ws_size,
                              hipStream_t stream)
{
    const float* qv = (const float*)d_in[0];
    const float* kv = (const float*)d_in[1];
    const float* vv = (const float*)d_in[2];
    const int*   mask = (const int*)d_in[3];
    const float* Wq = (const float*)d_in[4];
    const float* Wk = (const float*)d_in[5];
    const float* Wv = (const float*)d_in[6];
    float* out = (float*)d_out;

    // ws layout: Wf x3 | q/k/v bf16 | O partials bf16 | M,L fp32  (~24.2 MB)
    unsigned short* wf    = (unsigned short*)d_ws;
    unsigned short* qbuf  = wf + 3 * C_ * HS_;
    unsigned short* kbuf  = qbuf + (long)B_ * T_ * HS_;
    unsigned short* vbuf  = kbuf + (long)B_ * T_ * HS_;
    unsigned short* Opart = vbuf + (long)B_ * T_ * HS_;
    float* Mpart = (float*)(Opart + (long)B_ * 32 * NS * 4096);
    float* Lpart = Mpart + (long)B_ * 32 * NS * 64;

    prep_wt<<<48, 256, 0, stream>>>(Wq, Wk, Wv, wf);
    proj_kernel<<<3072, 256, 0, stream>>>(qv, kv, vv, wf, qbuf, kbuf, vbuf);
    attn_partial<<<B_ * 32 * NS, 256, 0, stream>>>(qbuf, kbuf, vbuf, mask, Opart, Mpart, Lpart);
    attn_combine<<<B_ * 32 * 2, 256, 0, stream>>>(Opart, Mpart, Lpart, out);
}

// Round 6
// 250.428 us; speedup vs baseline: 1.0577x; 1.0066x over previous
//
#include <hip/hip_runtime.h>
#include <hip/hip_bf16.h>
#include <cmath>
#include <stdint.h>

#define B_ 8
#define T_ 2048
#define C_ 1024
#define HS_ 64
#define NS 8           // key splits per q-tile
#define LP 72          // attn LDS row stride in shorts
#define XLS 1032       // proj X LDS row stride in shorts (516 dw ≡ 4 mod 32 -> 2-way b128, free)

typedef __attribute__((ext_vector_type(8))) short short8;    // 8 bf16 (4 VGPRs) - MFMA A/B frag
typedef __attribute__((ext_vector_type(4))) float floatx4;   // MFMA C/D frag

__device__ inline unsigned short f2bf(float f) {
    union { float f; unsigned u; } v; v.f = f;
    unsigned r = v.u + 0x7FFF + ((v.u >> 16) & 1);   // RNE
    return (unsigned short)(r >> 16);
}
__device__ inline unsigned pk2bf(float a, float b) {   // -> v_cvt_pk_bf16_f32
    union { __hip_bfloat162 h; unsigned u; } v;
    v.h = __float22bfloat162_rn(float2{a, b});
    return v.u;
}
__device__ inline float bf2f(unsigned short u) {
    union { unsigned u; float f; } w; w.u = ((unsigned)u) << 16; return w.f;
}

// ---------------------------------------------------------------------------
// Kernel 1: W [C x HS] fp32 -> Wf in MFMA B-fragment order, bf16.
// Wf unit (ks, nt, lane=quad*16+l16) holds 8 bf16:
//   W[ks*32 + quad*8 + j][nt*16 + l16],  j = 0..7
// so proj's B-frag load for (ks,nt) is ONE contiguous 1KB wave-load.
// ---------------------------------------------------------------------------
__global__ __launch_bounds__(256) void prep_wt(const float* __restrict__ Wq,
                                               const float* __restrict__ Wk,
                                               const float* __restrict__ Wv,
                                               unsigned short* __restrict__ wf) {
    int p   = blockIdx.x >> 4;        // 48 blocks: 3 proj x 16
    int blk = blockIdx.x & 15;
    const float* W = (p == 0) ? Wq : (p == 1) ? Wk : Wv;
    unsigned short* Wf = wf + p * 65536;
    #pragma unroll
    for (int it = 0; it < 16; ++it) {
        int idx = blk * 4096 + it * 256 + threadIdx.x;   // 0..65535, coalesced read
        int k = idx >> 6, col = idx & 63;
        int ks = k >> 5, quad = (k >> 3) & 3, j = k & 7;
        int nt = col >> 4, l16 = col & 15;
        Wf[(ks * 256 + nt * 64 + quad * 16 + l16) * 8 + j] = f2bf(W[idx]);
    }
}

// ---------------------------------------------------------------------------
// Kernel 2: projections. X [16384x1024] fp32 @ W [1024x64] -> bf16 [16384x64]
//
// Round-6: channel-uniform X streaming. Evidence: 5 structures (LDS-staged /
// direct / W-in-LDS / frag-ordered / 4-way-K-split), occupancy 30% AND 59%,
// ILP present (r2, VGPR=88) and absent (r3/r5, VGPR=36) -- ALL land at
// 82-95us, ~2.4 TB/s effective. The one invariant: X wave-loads put lane
// l16 on ROW -> 16 rows x 4KB stride x <=512B contiguous each. With 256B
// HBM channel interleave, channel = (16*row + col/256) mod Nch: each
// instruction hits ~2 of 32 channels -> channel queueing caps BW at ~38%
// of m13's 6.3 TB/s (which used 1KB-contiguous wave-loads). Fix: a 16-row
// tile IS 64KB contiguous; stage it linearly (thread tid reads 16B at
// base + it*4096 + tid*16 -> every wave-load 1KB contiguous, block streams
// 64KB linearly), cvt to bf16 into LDS [16][1032], then round-5's proven
// 4-way K-split MFMA + LDS reduce. Wf path (L2-hot, shown irrelevant)
// unchanged. LDS 46KB -> 3 blocks/CU (occupancy shown irrelevant in r5).
// grid = 3072 (3 proj x 1024 tiles), block = 256.
// ---------------------------------------------------------------------------
__global__ __launch_bounds__(256) void proj_kernel(
    const float* __restrict__ qv, const float* __restrict__ kv, const float* __restrict__ vv,
    const unsigned short* __restrict__ wf,
    unsigned short* __restrict__ qb, unsigned short* __restrict__ kb, unsigned short* __restrict__ vb)
{
    __shared__ unsigned short Xl[16 * XLS];   // 33 KB bf16 X tile
    __shared__ float rlds[3][16][68];         // 13 KB reduce scratch

    const int tid  = threadIdx.x;
    const int wave = tid >> 6, lane = tid & 63, quad = lane >> 4, l16 = lane & 15;
    const int p    = blockIdx.x >> 10;          // projection (1024 tiles each)
    const int tile = blockIdx.x & 1023;         // 16-row tile

    const float* X = (p == 0) ? qv : (p == 1) ? kv : vv;
    unsigned short* Ob = (p == 0) ? qb : (p == 1) ? kb : vb;
    const unsigned short* Wf = wf + p * 65536;
    const float oscale = (p == 0) ? 0.125f : 1.0f;   // fold HS^-0.5 into Q

    // ---- stage: 64 KB contiguous -> LDS bf16, linear channel sweep ----
    const float* Xt = X + (long)tile * 16 * C_;   // 16 rows, contiguous 64 KB
    #pragma unroll
    for (int g = 0; g < 2; ++g) {
        floatx4 xv[8];
        #pragma unroll
        for (int i = 0; i < 8; ++i)
            xv[i] = *(const floatx4*)(Xt + (g * 8 + i) * 1024 + tid * 4);
        #pragma unroll
        for (int i = 0; i < 8; ++i) {
            unsigned u0 = pk2bf(xv[i][0], xv[i][1]);
            unsigned u1 = pk2bf(xv[i][2], xv[i][3]);
            unsigned* d = (unsigned*)&Xl[(g * 8 + i) * XLS + tid * 4];
            d[0] = u0; d[1] = u1;
        }
    }
    __syncthreads();

    // ---- compute: wave owns K quarter [wave*256, wave*256+256) ----
    const unsigned short* wp = Wf + (wave * 8) * 4 * 512 + lane * 8;

    floatx4 acc[4] = { {0,0,0,0},{0,0,0,0},{0,0,0,0},{0,0,0,0} };

    short8 wq[2][4];
    #pragma unroll
    for (int nt = 0; nt < 4; ++nt) wq[0][nt] = *(const short8*)(wp + nt * 512);
    #pragma unroll
    for (int nt = 0; nt < 4; ++nt) wq[1][nt] = *(const short8*)(wp + (4 + nt) * 512);

    #pragma unroll
    for (int s = 0; s < 8; ++s) {
        const int bi = s & 1;
        short8 b0 = wq[bi][0], b1 = wq[bi][1], b2 = wq[bi][2], b3 = wq[bi][3];
        if (s + 2 < 8) {
            #pragma unroll
            for (int nt = 0; nt < 4; ++nt)
                wq[bi][nt] = *(const short8*)(wp + ((s + 2) * 4 + nt) * 512);
        }
        short8 af = *(const short8*)&Xl[l16 * XLS + wave * 256 + s * 32 + quad * 8];

        acc[0] = __builtin_amdgcn_mfma_f32_16x16x32_bf16(af, b0, acc[0], 0, 0, 0);
        acc[1] = __builtin_amdgcn_mfma_f32_16x16x32_bf16(af, b1, acc[1], 0, 0, 0);
        acc[2] = __builtin_amdgcn_mfma_f32_16x16x32_bf16(af, b2, acc[2], 0, 0, 0);
        acc[3] = __builtin_amdgcn_mfma_f32_16x16x32_bf16(af, b3, acc[3], 0, 0, 0);
    }

    // ---- 4-way K reduction through LDS (one barrier) ----
    if (wave) {
        #pragma unroll
        for (int nt = 0; nt < 4; ++nt)
            #pragma unroll
            for (int r = 0; r < 4; ++r)
                rlds[wave - 1][quad * 4 + r][nt * 16 + l16] = acc[nt][r];
    }
    __syncthreads();
    if (wave == 0) {
        #pragma unroll
        for (int nt = 0; nt < 4; ++nt)
            #pragma unroll
            for (int r = 0; r < 4; ++r)
                acc[nt][r] += rlds[0][quad * 4 + r][nt * 16 + l16]
                            + rlds[1][quad * 4 + r][nt * 16 + l16]
                            + rlds[2][quad * 4 + r][nt * 16 + l16];

        // C layout: row = tile*16 + quad*4 + r, col = nt*16 + l16
        unsigned short* op = Ob + ((long)tile * 16 + quad * 4) * HS_ + l16;
        #pragma unroll
        for (int nt = 0; nt < 4; ++nt)
            #pragma unroll
            for (int r = 0; r < 4; ++r)
                op[r * HS_ + nt * 16] = f2bf(acc[nt][r] * oscale);
    }
}

// ---------------------------------------------------------------------------
// Kernel 3a: flash attention partials with key-split.
// grid = 8b x 32qt x NS splits = 2048 WGs, block = 256 (4 waves x 16 q-rows).
// ---------------------------------------------------------------------------
__global__ __launch_bounds__(256) void attn_partial(
    const unsigned short* __restrict__ qb, const unsigned short* __restrict__ kb,
    const unsigned short* __restrict__ vb, const int* __restrict__ mask,
    unsigned short* __restrict__ Opart, float* __restrict__ Mpart, float* __restrict__ Lpart)
{
    const int s  = blockIdx.x & (NS - 1);
    const int bq = blockIdx.x >> 3;          // b*32 + qt
    const int qt = bq & 31;
    const int b  = bq >> 5;
    if (s > qt) return;                       // empty split; combine skips it

    __shared__ unsigned short Klds[64 * LP];      // K chunk [key][feat]
    __shared__ unsigned short Vt[64 * LP];        // V chunk transposed [feat][key]
    __shared__ unsigned short Plds[4][16 * LP];   // per-wave P scratch [qrow][key]

    const int tid = threadIdx.x;
    const int wave = tid >> 6, lane = tid & 63, quad = lane >> 4, l16 = lane & 15;

    // Q fragments (A-operand: m = l16, k = quad*8+j); scale folded in.
    const int qrow = qt * 64 + wave * 16 + l16;
    const unsigned short* qp = qb + ((long)(b * T_ + qrow)) * HS_;
    short8 aq0 = *(const short8*)&qp[0  + quad * 8];
    short8 aq1 = *(const short8*)&qp[32 + quad * 8];

    floatx4 acc_o[4] = { {0,0,0,0},{0,0,0,0},{0,0,0,0},{0,0,0,0} };
    float m_r[4] = { -INFINITY, -INFINITY, -INFINITY, -INFINITY };
    float l_r[4] = { 0.f, 0.f, 0.f, 0.f };

    const int rowg = qt * 64 + wave * 16 + quad * 4;

    const int skey = tid >> 3;
    const int sf8  = (tid & 7) * 8;
    const int vp = tid & 31, vg = tid >> 5;

    for (int c = s; c <= qt; c += NS) {
        const int kc = c * 64;
        #pragma unroll
        for (int it = 0; it < 2; ++it) {
            int key = it * 32 + skey;
            *(short8*)&Klds[key * LP + sf8] =
                *(const short8*)&kb[((long)(b * T_ + kc + key)) * HS_ + sf8];
        }
        {
            const unsigned short* v0p = &vb[((long)(b * T_ + kc + 2 * vp)) * HS_ + vg * 8];
            short8 v0 = *(const short8*)v0p;
            short8 v1 = *(const short8*)(v0p + HS_);
            #pragma unroll
            for (int j = 0; j < 8; ++j) {
                unsigned pr = (unsigned)(unsigned short)v0[j] |
                              ((unsigned)(unsigned short)v1[j] << 16);
                *(unsigned*)&Vt[(vg * 8 + j) * LP + 2 * vp] = pr;
            }
        }
        __syncthreads();

        floatx4 sv[4];
        #pragma unroll
        for (int kt = 0; kt < 4; ++kt) {
            floatx4 a = {0.f, 0.f, 0.f, 0.f};
            short8 bk0 = *(short8*)&Klds[(kt * 16 + l16) * LP + 0  + quad * 8];
            short8 bk1 = *(short8*)&Klds[(kt * 16 + l16) * LP + 32 + quad * 8];
            a = __builtin_amdgcn_mfma_f32_16x16x32_bf16(aq0, bk0, a, 0, 0, 0);
            a = __builtin_amdgcn_mfma_f32_16x16x32_bf16(aq1, bk1, a, 0, 0, 0);
            sv[kt] = a;
        }

        const bool lastc = (c == qt);
        #pragma unroll
        for (int kt = 0; kt < 4; ++kt) {
            int key = kc + kt * 16 + l16;
            int mk = mask[b * T_ + key];
            #pragma unroll
            for (int r = 0; r < 4; ++r) {
                bool dead = (mk == 0) || (lastc && key > rowg + r);
                if (dead) sv[kt][r] = -INFINITY;
            }
        }

        float alpha[4];
        #pragma unroll
        for (int r = 0; r < 4; ++r) {
            float mx = fmaxf(fmaxf(sv[0][r], sv[1][r]), fmaxf(sv[2][r], sv[3][r]));
            #pragma unroll
            for (int off = 1; off < 16; off <<= 1)
                mx = fmaxf(mx, __shfl_xor(mx, off));
            float mn = fmaxf(m_r[r], mx);
            float a_ = __expf(m_r[r] - mn);
            float ps = 0.f;
            #pragma unroll
            for (int kt = 0; kt < 4; ++kt) {
                float pv = __expf(sv[kt][r] - mn);
                sv[kt][r] = pv;
                ps += pv;
            }
            #pragma unroll
            for (int off = 1; off < 16; off <<= 1)
                ps += __shfl_xor(ps, off);
            l_r[r] = l_r[r] * a_ + ps;
            m_r[r] = mn;
            alpha[r] = a_;
        }
        #pragma unroll
        for (int nt = 0; nt < 4; ++nt)
            #pragma unroll
            for (int r = 0; r < 4; ++r)
                acc_o[nt][r] *= alpha[r];

        unsigned short* pl = Plds[wave];
        #pragma unroll
        for (int kt = 0; kt < 4; ++kt)
            #pragma unroll
            for (int r = 0; r < 4; ++r)
                pl[(quad * 4 + r) * LP + kt * 16 + l16] = f2bf(sv[kt][r]);
        short8 ap0 = *(short8*)&pl[l16 * LP + 0  + quad * 8];
        short8 ap1 = *(short8*)&pl[l16 * LP + 32 + quad * 8];

        #pragma unroll
        for (int nt = 0; nt < 4; ++nt) {
            short8 bv0 = *(short8*)&Vt[(nt * 16 + l16) * LP + 0  + quad * 8];
            short8 bv1 = *(short8*)&Vt[(nt * 16 + l16) * LP + 32 + quad * 8];
            acc_o[nt] = __builtin_amdgcn_mfma_f32_16x16x32_bf16(ap0, bv0, acc_o[nt], 0, 0, 0);
            acc_o[nt] = __builtin_amdgcn_mfma_f32_16x16x32_bf16(ap1, bv1, acc_o[nt], 0, 0, 0);
        }
        __syncthreads();
    }

    // write partials: O unnormalized (bf16), m/l fp32
    unsigned short* Op = Opart + (long)blockIdx.x * 4096;
    #pragma unroll
    for (int nt = 0; nt < 4; ++nt)
        #pragma unroll
        for (int r = 0; r < 4; ++r)
            Op[(wave * 16 + quad * 4 + r) * 64 + nt * 16 + l16] = f2bf(acc_o[nt][r]);
    if (l16 == 0) {
        #pragma unroll
        for (int r = 0; r < 4; ++r) {
            int rl = wave * 16 + quad * 4 + r;
            Mpart[(long)blockIdx.x * 64 + rl] = m_r[r];
            Lpart[(long)blockIdx.x * 64 + rl] = l_r[r];
        }
    }
}

// ---------------------------------------------------------------------------
// Kernel 3b: combine split partials. grid = 8b x 32qt x 2 = 512, block = 256.
// ---------------------------------------------------------------------------
__global__ __launch_bounds__(256) void attn_combine(
    const unsigned short* __restrict__ Opart, const float* __restrict__ Mpart,
    const float* __restrict__ Lpart, float* __restrict__ out)
{
    const int half = blockIdx.x & 1;
    const int bq = blockIdx.x >> 1;
    const int qt = bq & 31;
    const int b  = bq >> 5;
    const int nsp = (qt + 1 < NS) ? qt + 1 : NS;

    const int row  = (threadIdx.x >> 3) + half * 32;   // 0..63
    const int colg = (threadIdx.x & 7) * 8;
    const long base = (long)bq * NS;

    float M = -INFINITY;
    #pragma unroll
    for (int sp = 0; sp < NS; ++sp)
        if (sp < nsp) M = fmaxf(M, Mpart[(base + sp) * 64 + row]);

    float w[NS];
    float L = 0.f;
    #pragma unroll
    for (int sp = 0; sp < NS; ++sp)
        if (sp < nsp) {
            float e = __expf(Mpart[(base + sp) * 64 + row] - M);
            w[sp] = e;
            L += e * Lpart[(base + sp) * 64 + row];
        }

    float acc[8] = {0,0,0,0,0,0,0,0};
    #pragma unroll
    for (int sp = 0; sp < NS; ++sp)
        if (sp < nsp) {
            const unsigned short* Op = Opart + (base + sp) * 4096 + row * 64 + colg;
            short8 o = *(const short8*)Op;
            float ws = w[sp];
            #pragma unroll
            for (int j = 0; j < 8; ++j)
                acc[j] += ws * bf2f((unsigned short)o[j]);
        }

    float inv = 1.0f / L;
    float* op = out + ((long)(b * T_ + qt * 64 + row)) * HS_ + colg;
    floatx4 o0 = { acc[0] * inv, acc[1] * inv, acc[2] * inv, acc[3] * inv };
    floatx4 o1 = { acc[4] * inv, acc[5] * inv, acc[6] * inv, acc[7] * inv };
    *(floatx4*)op = o0;
    *(floatx4*)(op + 4) = o1;
}

// ---------------------------------------------------------------------------
extern "C" void kernel_launch(void* const* d_in, const int* in_sizes, int n_in,
                              void* d_out, int out_size, void* d_ws, size_t ws_size,
                              hipStream_t stream)
{
    const float* qv = (const float*)d_in[0];
    const float* kv = (const float*)d_in[1];
    const float* vv = (const float*)d_in[2];
    const int*   mask = (const int*)d_in[3];
    const float* Wq = (const float*)d_in[4];
    const float* Wk = (const float*)d_in[5];
    const float* Wv = (const float*)d_in[6];
    float* out = (float*)d_out;

    // ws layout: Wf x3 | q/k/v bf16 | O partials bf16 | M,L fp32  (~24.2 MB)
    unsigned short* wf    = (unsigned short*)d_ws;
    unsigned short* qbuf  = wf + 3 * C_ * HS_;
    unsigned short* kbuf  = qbuf + (long)B_ * T_ * HS_;
    unsigned short* vbuf  = kbuf + (long)B_ * T_ * HS_;
    unsigned short* Opart = vbuf + (long)B_ * T_ * HS_;
    float* Mpart = (float*)(Opart + (long)B_ * 32 * NS * 4096);
    float* Lpart = Mpart + (long)B_ * 32 * NS * 64;

    prep_wt<<<48, 256, 0, stream>>>(Wq, Wk, Wv, wf);
    proj_kernel<<<3072, 256, 0, stream>>>(qv, kv, vv, wf, qbuf, kbuf, vbuf);
    attn_partial<<<B_ * 32 * NS, 256, 0, stream>>>(qbuf, kbuf, vbuf, mask, Opart, Mpart, Lpart);
    attn_combine<<<B_ * 32 * 2, 256, 0, stream>>>(Opart, Mpart, Lpart, out);
}